// Round 2
// baseline (980.638 us; speedup 1.0000x reference)
//
#include <hip/hip_runtime.h>
#include <cfloat>

// Farthest Point Sampling: B=32, N=200000, M=128.
// Persistent kernel: 8 blocks/batch x 512 threads; each thread owns 49 points
// in VGPRs (xyz) + running min-dist in LDS (b128-packed). 127 sequential
// global argmax rounds via per-batch 8-block spin barrier in d_ws.
#define B_    32
#define N_    200000
#define M_    128
#define BPB   8                  // blocks per batch
#define T_    512                // threads per block
#define PT    49                 // points per thread (8*512*49 = 200704 >= N)
#define JB    13                 // ceil(PT/4) float4 groups
#define CHUNK (T_ * PT)          // 25088 points per block

// ws layout (ints): [0..2047] per-batch barrier counters (stride 64)
//                   [2048.. ] candidate slots: ((b*BPB+c)*2 + parity)*8 ints
#define CTR_STRIDE 64
#define CAND_BASE  2048
#define SPIN_CAP   (1 << 18)     // ~14ms safety valve: wrong answer, never a hang

__global__ __launch_bounds__(T_, 2)
void fps_kernel(const float* __restrict__ pts, int* __restrict__ out, int* __restrict__ ws) {
  const int tid  = threadIdx.x;
  const int bid  = blockIdx.x;
  const int b    = bid >> 3;       // batch
  const int c    = bid & 7;        // chunk within batch
  const int wave = tid >> 6;
  const int lane = tid & 63;

  const float* __restrict__ P = pts + (size_t)b * (size_t)(N_ * 3);
  int* ctr  = ws + b * CTR_STRIDE;
  int* cand = ws + CAND_BASE;

  const int g0 = c * CHUNK + tid;  // this thread's j=0 global point index

  // 13*512*16B = 104 KiB -> forces exactly 1 block/CU (co-residency guarantee)
  __shared__ float smd[JB][T_][4];
  __shared__ float sv[T_ / 64];
  __shared__ int   si[T_ / 64];
  __shared__ int   wfar;
  __shared__ float wx, wy, wz;

  // ---- one-time load: points into registers, min-dist init in LDS ----
  float px[PT], py[PT], pz[PT];
  #pragma unroll
  for (int jb = 0; jb < JB; ++jb) {
    float m4[4];
    #pragma unroll
    for (int q = 0; q < 4; ++q) {
      int j = jb * 4 + q;
      if (j < PT) {
        int g = g0 + j * T_;
        if (g < N_) {
          const float* p = P + (size_t)g * 3;
          px[j] = p[0]; py[j] = p[1]; pz[j] = p[2];
          m4[q] = __builtin_huge_valf();
        } else {
          px[j] = 0.f; py[j] = 0.f; pz[j] = 0.f;
          m4[q] = -FLT_MAX;                      // padded: never selected
        }
      } else {
        m4[q] = -FLT_MAX;
      }
    }
    float4 v4; v4.x = m4[0]; v4.y = m4[1]; v4.z = m4[2]; v4.w = m4[3];
    *(float4*)(&smd[jb][tid][0]) = v4;
  }

  float cx = P[0], cy = P[1], cz = P[2];   // initial center = point 0
  int far = 0;
  if (c == 0 && tid == 0) out[b * M_ + 0] = 0;

  for (int it = 1; it < M_; ++it) {
    // ---- exclusion: owner thread pre-sets its own md entry to -1 ----
    // (min(-1, d>=0) == -1 matches reference's min-then-set order)
    int r = far - c * CHUNK;
    if (r >= 0 && r < CHUNK && (r & (T_ - 1)) == tid) {
      int jf = r >> 9;                     // r / T_
      smd[jf >> 2][tid][jf & 3] = -1.0f;
    }

    // ---- distance + running-min + 4-chain local argmax ----
    float bv[4] = {-FLT_MAX, -FLT_MAX, -FLT_MAX, -FLT_MAX};
    int   bi[4] = {0x7FFFFFFF, 0x7FFFFFFF, 0x7FFFFFFF, 0x7FFFFFFF};
    #pragma unroll
    for (int jb = 0; jb < JB; ++jb) {
      float4 m4 = *(const float4*)(&smd[jb][tid][0]);
      float nm[4] = {m4.x, m4.y, m4.z, m4.w};
      #pragma unroll
      for (int q = 0; q < 4; ++q) {
        int j = jb * 4 + q;
        if (j < PT) {
          float dx = __fsub_rn(px[j], cx);
          float dy = __fsub_rn(py[j], cy);
          float dz = __fsub_rn(pz[j], cz);
          // numpy: ((dx*dx + dy*dy) + dz*dz), rn, no FMA contraction
          float d  = __fadd_rn(__fadd_rn(__fmul_rn(dx, dx), __fmul_rn(dy, dy)),
                               __fmul_rn(dz, dz));
          float m  = fminf(nm[q], d);        // np.minimum
          nm[q] = m;
          bool take = m > bv[q];             // ascending index within chain: strict >
          bv[q] = take ? m : bv[q];
          bi[q] = take ? (g0 + j * T_) : bi[q];
        }
      }
      float4 w4; w4.x = nm[0]; w4.y = nm[1]; w4.z = nm[2]; w4.w = nm[3];
      *(float4*)(&smd[jb][tid][0]) = w4;
    }
    // merge 4 chains (tie -> smaller index = first occurrence)
    float tv = bv[0]; int ti = bi[0];
    #pragma unroll
    for (int q = 1; q < 4; ++q) {
      bool take = (bv[q] > tv) || (bv[q] == tv && bi[q] < ti);
      tv = take ? bv[q] : tv;
      ti = take ? bi[q] : ti;
    }

    // ---- wave reduction (64 lanes) ----
    #pragma unroll
    for (int o = 32; o > 0; o >>= 1) {
      float ov = __shfl_xor(tv, o);
      int   oi = __shfl_xor(ti, o);
      bool take = (ov > tv) || (ov == tv && oi < ti);
      tv = take ? ov : tv;
      ti = take ? oi : ti;
    }
    if (lane == 0) { sv[wave] = tv; si[wave] = ti; }
    __syncthreads();

    if (wave == 0) {
      // ---- cross-wave reduction (8 entries) ----
      float v8 = (lane < T_ / 64) ? sv[lane] : -FLT_MAX;
      int   i8 = (lane < T_ / 64) ? si[lane] : 0x7FFFFFFF;
      #pragma unroll
      for (int o = 4; o > 0; o >>= 1) {
        float ov = __shfl_xor(v8, o);
        int   oi = __shfl_xor(i8, o);
        bool take = (ov > v8) || (ov == v8 && oi < i8);
        v8 = take ? ov : v8;
        i8 = take ? oi : i8;
      }

      if (lane == 0) {
        // publish block candidate (parity double-buffered), arrive at barrier
        int* slot = cand + (((b * BPB + c) * 2 + (it & 1)) * 8);
        __hip_atomic_store(slot + 0, __float_as_int(v8), __ATOMIC_RELAXED, __HIP_MEMORY_SCOPE_AGENT);
        __hip_atomic_store(slot + 1, i8,                 __ATOMIC_RELAXED, __HIP_MEMORY_SCOPE_AGENT);
        __hip_atomic_fetch_add(ctr, 1, __ATOMIC_RELEASE, __HIP_MEMORY_SCOPE_AGENT);
        const int target = BPB * it;         // monotonic counter, memset'd per launch
        int sp = 0;
        while (__hip_atomic_load(ctr, __ATOMIC_ACQUIRE, __HIP_MEMORY_SCOPE_AGENT) < target) {
          __builtin_amdgcn_s_sleep(2);
          if (++sp > SPIN_CAP) break;        // never hang the container
        }
      }
      // reconverged: lanes 0..7 fetch the 8 block candidates
      float cv = -FLT_MAX; int ci = 0x7FFFFFFF;
      if (lane < BPB) {
        int* slot = cand + (((b * BPB + lane) * 2 + (it & 1)) * 8);
        cv = __int_as_float(__hip_atomic_load(slot + 0, __ATOMIC_RELAXED, __HIP_MEMORY_SCOPE_AGENT));
        ci =                __hip_atomic_load(slot + 1, __ATOMIC_RELAXED, __HIP_MEMORY_SCOPE_AGENT);
      }
      #pragma unroll
      for (int o = 4; o > 0; o >>= 1) {
        float ov = __shfl_xor(cv, o);
        int   oi = __shfl_xor(ci, o);
        bool take = (ov > cv) || (ov == cv && oi < ci);
        cv = take ? ov : cv;
        ci = take ? oi : ci;
      }
      if (lane == 0) {
        const float* pw = P + (size_t)ci * 3;  // L3-resident: points streamed once
        wfar = ci; wx = pw[0]; wy = pw[1]; wz = pw[2];
        if (c == 0) out[b * M_ + it] = ci;
      }
    }
    __syncthreads();
    far = wfar; cx = wx; cy = wy; cz = wz;
  }
}

extern "C" void kernel_launch(void* const* d_in, const int* in_sizes, int n_in,
                              void* d_out, int out_size, void* d_ws, size_t ws_size,
                              hipStream_t stream) {
  const float* pts = (const float*)d_in[0];
  int*         out = (int*)d_out;
  int*         ws  = (int*)d_ws;

  // zero barrier counters every launch (graph-capture-safe memset node)
  hipMemsetAsync(d_ws, 0, CTR_STRIDE * B_ * sizeof(int), stream);

  // Plain launch: 104 KiB LDS/block forces 1 block/CU; grid == 256 == CU count
  // on an otherwise-idle GPU -> all blocks co-resident (no coop API needed).
  fps_kernel<<<dim3(B_ * BPB), dim3(T_), 0, stream>>>(pts, out, ws);
}

// Round 3
// 936.315 us; speedup vs baseline: 1.0473x; 1.0473x over previous
//
#include <hip/hip_runtime.h>
#include <cfloat>

// Farthest Point Sampling: B=32, N=200000, M=128.
// Persistent kernel: 8 blocks/batch x 512 threads; each thread owns 49 points
// in VGPRs (xyz, pinned via asm to defeat rematerialization) + running
// min-dist in LDS. 127 sequential global argmax rounds via per-batch 8-block
// spin barrier in d_ws.
#define B_    32
#define N_    200000
#define M_    128
#define BPB   8                  // blocks per batch
#define T_    512                // threads per block
#define PT    49                 // points per thread (8*512*49 = 200704 >= N)
#define JB    13                 // ceil(PT/4) float4 groups
#define CHUNK (T_ * PT)          // 25088 points per block

// ws layout (ints): [0..2047] per-batch barrier counters (stride 64)
//                   [2048.. ] candidate slots: ((b*BPB+c)*2 + parity)*8 ints
#define CTR_STRIDE 64
#define CAND_BASE  2048
#define SPIN_CAP   (1 << 18)     // ~14ms safety valve: wrong answer, never a hang

__global__ __launch_bounds__(T_)
__attribute__((amdgpu_waves_per_eu(2, 2)))   // pin allocator to 256-VGPR budget
void fps_kernel(const float* __restrict__ pts, int* __restrict__ out, int* __restrict__ ws) {
  const int tid  = threadIdx.x;
  const int bid  = blockIdx.x;
  const int b    = bid >> 3;       // batch
  const int c    = bid & 7;        // chunk within batch
  const int wave = tid >> 6;
  const int lane = tid & 63;

  const float* __restrict__ P = pts + (size_t)b * (size_t)(N_ * 3);
  int* ctr  = ws + b * CTR_STRIDE;
  int* cand = ws + CAND_BASE;

  const int g0 = c * CHUNK + tid;  // this thread's j=0 global point index

  // 13*512*16B = 104 KiB -> forces exactly 1 block/CU (co-residency guarantee)
  __shared__ float smd[JB][T_][4];
  __shared__ float sv[T_ / 64];
  __shared__ int   si[T_ / 64];
  __shared__ int   wfar;
  __shared__ float wx, wy, wz;

  // ---- one-time load: points into registers, min-dist init in LDS ----
  float px[PT], py[PT], pz[PT];
  #pragma unroll
  for (int jb = 0; jb < JB; ++jb) {
    float m4[4];
    #pragma unroll
    for (int q = 0; q < 4; ++q) {
      int j = jb * 4 + q;
      if (j < PT) {
        int g = g0 + j * T_;
        if (g < N_) {
          const float* p = P + (size_t)g * 3;
          px[j] = p[0]; py[j] = p[1]; pz[j] = p[2];
          m4[q] = __builtin_huge_valf();
        } else {
          px[j] = 0.f; py[j] = 0.f; pz[j] = 0.f;
          m4[q] = -FLT_MAX;                      // padded: never selected
        }
      } else {
        m4[q] = -FLT_MAX;
      }
    }
    float4 v4; v4.x = m4[0]; v4.y = m4[1]; v4.z = m4[2]; v4.w = m4[3];
    *(float4*)(&smd[jb][tid][0]) = v4;
  }

  // Pin xyz in VGPRs: SSA origin becomes the asm -> re-loading from global is
  // no longer a legal rematerialization for the register allocator.
  #pragma unroll
  for (int j = 0; j < PT; ++j) {
    asm volatile("" : "+v"(px[j]), "+v"(py[j]), "+v"(pz[j]));
  }

  float cx = P[0], cy = P[1], cz = P[2];   // initial center = point 0
  int far = 0;
  if (c == 0 && tid == 0) out[b * M_ + 0] = 0;

  for (int it = 1; it < M_; ++it) {
    // ---- exclusion: owner thread pre-sets its own md entry to -1 ----
    // (min(-1, d>=0) == -1 matches reference's min-then-set order)
    int r = far - c * CHUNK;
    if (r >= 0 && r < CHUNK && (r & (T_ - 1)) == tid) {
      int jf = r >> 9;                     // r / T_
      smd[jf >> 2][tid][jf & 3] = -1.0f;
    }

    // ---- distance + running-min + 4-chain local argmax ----
    float bv[4] = {-FLT_MAX, -FLT_MAX, -FLT_MAX, -FLT_MAX};
    int   bi[4] = {0x7FFFFFFF, 0x7FFFFFFF, 0x7FFFFFFF, 0x7FFFFFFF};
    #pragma unroll
    for (int jb = 0; jb < JB; ++jb) {
      float4 m4 = *(const float4*)(&smd[jb][tid][0]);
      float nm[4] = {m4.x, m4.y, m4.z, m4.w};
      #pragma unroll
      for (int q = 0; q < 4; ++q) {
        int j = jb * 4 + q;
        if (j < PT) {
          float dx = __fsub_rn(px[j], cx);
          float dy = __fsub_rn(py[j], cy);
          float dz = __fsub_rn(pz[j], cz);
          // numpy: ((dx*dx + dy*dy) + dz*dz), rn, no FMA contraction
          float d  = __fadd_rn(__fadd_rn(__fmul_rn(dx, dx), __fmul_rn(dy, dy)),
                               __fmul_rn(dz, dz));
          float m  = fminf(nm[q], d);        // np.minimum
          nm[q] = m;
          bool take = m > bv[q];             // ascending index within chain: strict >
          bv[q] = take ? m : bv[q];
          bi[q] = take ? (g0 + j * T_) : bi[q];
        }
      }
      float4 w4; w4.x = nm[0]; w4.y = nm[1]; w4.z = nm[2]; w4.w = nm[3];
      *(float4*)(&smd[jb][tid][0]) = w4;
    }
    // merge 4 chains (tie -> smaller index = first occurrence)
    float tv = bv[0]; int ti = bi[0];
    #pragma unroll
    for (int q = 1; q < 4; ++q) {
      bool take = (bv[q] > tv) || (bv[q] == tv && bi[q] < ti);
      tv = take ? bv[q] : tv;
      ti = take ? bi[q] : ti;
    }

    // ---- wave reduction (64 lanes) ----
    #pragma unroll
    for (int o = 32; o > 0; o >>= 1) {
      float ov = __shfl_xor(tv, o);
      int   oi = __shfl_xor(ti, o);
      bool take = (ov > tv) || (ov == tv && oi < ti);
      tv = take ? ov : tv;
      ti = take ? oi : ti;
    }
    if (lane == 0) { sv[wave] = tv; si[wave] = ti; }
    __syncthreads();

    if (wave == 0) {
      // ---- cross-wave reduction (8 entries) ----
      float v8 = (lane < T_ / 64) ? sv[lane] : -FLT_MAX;
      int   i8 = (lane < T_ / 64) ? si[lane] : 0x7FFFFFFF;
      #pragma unroll
      for (int o = 4; o > 0; o >>= 1) {
        float ov = __shfl_xor(v8, o);
        int   oi = __shfl_xor(i8, o);
        bool take = (ov > v8) || (ov == v8 && oi < i8);
        v8 = take ? ov : v8;
        i8 = take ? oi : i8;
      }

      if (lane == 0) {
        // publish block candidate (parity double-buffered), arrive at barrier
        int* slot = cand + (((b * BPB + c) * 2 + (it & 1)) * 8);
        __hip_atomic_store(slot + 0, __float_as_int(v8), __ATOMIC_RELAXED, __HIP_MEMORY_SCOPE_AGENT);
        __hip_atomic_store(slot + 1, i8,                 __ATOMIC_RELAXED, __HIP_MEMORY_SCOPE_AGENT);
        __hip_atomic_fetch_add(ctr, 1, __ATOMIC_RELEASE, __HIP_MEMORY_SCOPE_AGENT);
        const int target = BPB * it;         // monotonic counter, memset'd per launch
        int sp = 0;
        while (__hip_atomic_load(ctr, __ATOMIC_ACQUIRE, __HIP_MEMORY_SCOPE_AGENT) < target) {
          __builtin_amdgcn_s_sleep(2);
          if (++sp > SPIN_CAP) break;        // never hang the container
        }
      }
      // reconverged: lanes 0..7 fetch the 8 block candidates
      float cv = -FLT_MAX; int ci = 0x7FFFFFFF;
      if (lane < BPB) {
        int* slot = cand + (((b * BPB + lane) * 2 + (it & 1)) * 8);
        cv = __int_as_float(__hip_atomic_load(slot + 0, __ATOMIC_RELAXED, __HIP_MEMORY_SCOPE_AGENT));
        ci =                __hip_atomic_load(slot + 1, __ATOMIC_RELAXED, __HIP_MEMORY_SCOPE_AGENT);
      }
      #pragma unroll
      for (int o = 4; o > 0; o >>= 1) {
        float ov = __shfl_xor(cv, o);
        int   oi = __shfl_xor(ci, o);
        bool take = (ov > cv) || (ov == cv && oi < ci);
        cv = take ? ov : cv;
        ci = take ? oi : ci;
      }
      if (lane == 0) {
        const float* pw = P + (size_t)ci * 3;  // L3-resident: points streamed once
        wfar = ci; wx = pw[0]; wy = pw[1]; wz = pw[2];
        if (c == 0) out[b * M_ + it] = ci;
      }
    }
    __syncthreads();
    far = wfar; cx = wx; cy = wy; cz = wz;
  }
}

extern "C" void kernel_launch(void* const* d_in, const int* in_sizes, int n_in,
                              void* d_out, int out_size, void* d_ws, size_t ws_size,
                              hipStream_t stream) {
  const float* pts = (const float*)d_in[0];
  int*         out = (int*)d_out;
  int*         ws  = (int*)d_ws;

  // zero barrier counters every launch (graph-capture-safe memset node)
  hipMemsetAsync(d_ws, 0, CTR_STRIDE * B_ * sizeof(int), stream);

  // Plain launch: 104 KiB LDS/block forces 1 block/CU; grid == 256 == CU count
  // on an otherwise-idle GPU -> all blocks co-resident (no coop API needed).
  fps_kernel<<<dim3(B_ * BPB), dim3(T_), 0, stream>>>(pts, out, ws);
}

// Round 4
// 795.614 us; speedup vs baseline: 1.2326x; 1.1768x over previous
//
#include <hip/hip_runtime.h>
#include <cfloat>

// Farthest Point Sampling: B=32, N=200000, M=128.
// 8 blocks/batch x 1024 threads, 1 block/CU (LDS-forced). Per thread: 25
// points; md[25] + 13 points in VGPRs (~100 regs, fits the 128 cap of the
// 4-waves/SIMD regime -> no spill), 12 points in LDS float4 arrays
// (conflict-free, thread-private columns). Cross-block argmax via tag-encoded
// slots in d_ws (no atomicAdd serialization).
#define B_    32
#define N_    200000
#define M_    128
#define BPB   8                    // blocks per batch
#define T_    1024                 // threads per block
#define PV    13                   // points held in VGPRs
#define PL    12                   // points held in LDS (3 float4 groups)
#define PT    (PV + PL)            // 25 points/thread; 8*1024*25 = 204800 >= N
#define CHUNK (T_ * PT)            // 25600 points per block

#define SPIN_CAP (1 << 20)         // safety valve: never hang the container

struct __align__(32) Slot {
  unsigned long long tag;          // [63:32]=value bits, [24:7]=idx, [6:0]=iter
  unsigned long long xy;           // x bits | y bits << 32
  unsigned int       z;            // z bits
  unsigned int       pad[3];
};

__global__ __launch_bounds__(T_, 4)   // 4 waves/EU -> 128-VGPR budget (natural fit)
void fps_kernel(const float* __restrict__ pts, int* __restrict__ out,
                Slot* __restrict__ slots) {
  const int tid  = threadIdx.x;
  const int bid  = blockIdx.x;
  const int b    = bid >> 3;          // batch
  const int c    = bid & 7;           // chunk within batch
  const int wave = tid >> 6;
  const int lane = tid & 63;

  const float* __restrict__ P = pts + (size_t)b * (size_t)(N_ * 3);
  const int base = c * CHUNK + tid;   // global index of this thread's j=0 point

  // 9 x float4[1024] = 144 KiB -> exactly 1 block/CU (co-residency guarantee).
  // Thread-private columns: no cross-thread sharing, no sync, stride-16B
  // conflict-free ds_read_b128 pattern.
  __shared__ float4 sX[3][T_], sY[3][T_], sZ[3][T_];
  __shared__ float  sv[16];
  __shared__ int    si[16];
  __shared__ int    wfar;
  __shared__ float  wx, wy, wz;

  // ---- one-time load ----
  float vx[PV], vy[PV], vz[PV], md[PT];
  #pragma unroll
  for (int j = 0; j < PV; ++j) {
    int g = base + j * T_;
    if (g < N_) {
      const float* p = P + (size_t)g * 3;
      vx[j] = p[0]; vy[j] = p[1]; vz[j] = p[2];
      md[j] = __builtin_huge_valf();
    } else { vx[j] = vy[j] = vz[j] = 0.f; md[j] = -FLT_MAX; }
  }
  #pragma unroll
  for (int grp = 0; grp < 3; ++grp) {
    float qx[4], qy[4], qz[4];
    #pragma unroll
    for (int q = 0; q < 4; ++q) {
      int j = PV + grp * 4 + q;
      int g = base + j * T_;
      if (g < N_) {
        const float* p = P + (size_t)g * 3;
        qx[q] = p[0]; qy[q] = p[1]; qz[q] = p[2];
        md[j] = __builtin_huge_valf();
      } else { qx[q] = qy[q] = qz[q] = 0.f; md[j] = -FLT_MAX; }
    }
    sX[grp][tid] = make_float4(qx[0], qx[1], qx[2], qx[3]);
    sY[grp][tid] = make_float4(qy[0], qy[1], qy[2], qy[3]);
    sZ[grp][tid] = make_float4(qz[0], qz[1], qz[2], qz[3]);
  }

  float cx = P[0], cy = P[1], cz = P[2];   // initial center = point 0
  int   far = 0;
  if (c == 0 && tid == 0) out[b * M_ + 0] = 0;

  for (int it = 1; it < M_; ++it) {
    const int rj = far - base;       // this thread owns 'far' iff rj == j*T_

    // ---- distance + running-min + 4-chain argmax (all static indexing) ----
    float bv[4] = {-FLT_MAX, -FLT_MAX, -FLT_MAX, -FLT_MAX};
    int   bi[4] = {0x7FFFFFFF, 0x7FFFFFFF, 0x7FFFFFFF, 0x7FFFFFFF};

    #pragma unroll
    for (int j = 0; j < PV; ++j) {
      float dx = __fsub_rn(vx[j], cx);
      float dy = __fsub_rn(vy[j], cy);
      float dz = __fsub_rn(vz[j], cz);
      float d  = __fadd_rn(__fadd_rn(__fmul_rn(dx, dx), __fmul_rn(dy, dy)),
                           __fmul_rn(dz, dz));
      float m  = fminf(md[j], d);          // np.minimum
      m = (rj == j * T_) ? -1.0f : m;      // exclusion AFTER min (ref order)
      md[j] = m;
      const int q = j & 3;
      bool take = m > bv[q];               // ascending index in chain: strict >
      bv[q] = take ? m : bv[q];
      bi[q] = take ? (base + j * T_) : bi[q];
    }
    #pragma unroll
    for (int grp = 0; grp < 3; ++grp) {
      float4 qx = sX[grp][tid], qy = sY[grp][tid], qz = sZ[grp][tid];
      #pragma unroll
      for (int q4 = 0; q4 < 4; ++q4) {
        const int j = PV + grp * 4 + q4;
        float X = (q4 == 0) ? qx.x : (q4 == 1) ? qx.y : (q4 == 2) ? qx.z : qx.w;
        float Y = (q4 == 0) ? qy.x : (q4 == 1) ? qy.y : (q4 == 2) ? qy.z : qy.w;
        float Z = (q4 == 0) ? qz.x : (q4 == 1) ? qz.y : (q4 == 2) ? qz.z : qz.w;
        float dx = __fsub_rn(X, cx);
        float dy = __fsub_rn(Y, cy);
        float dz = __fsub_rn(Z, cz);
        float d  = __fadd_rn(__fadd_rn(__fmul_rn(dx, dx), __fmul_rn(dy, dy)),
                             __fmul_rn(dz, dz));
        float m  = fminf(md[j], d);
        m = (rj == j * T_) ? -1.0f : m;
        md[j] = m;
        const int q = j & 3;
        bool take = m > bv[q];
        bv[q] = take ? m : bv[q];
        bi[q] = take ? (base + j * T_) : bi[q];
      }
    }
    // merge 4 chains (tie -> smaller index = first occurrence)
    float tv = bv[0]; int ti = bi[0];
    #pragma unroll
    for (int q = 1; q < 4; ++q) {
      bool take = (bv[q] > tv) || (bv[q] == tv && bi[q] < ti);
      tv = take ? bv[q] : tv;
      ti = take ? bi[q] : ti;
    }

    // ---- wave reduction (64 lanes, value/index only) ----
    #pragma unroll
    for (int o = 32; o > 0; o >>= 1) {
      float ov = __shfl_xor(tv, o);
      int   oi = __shfl_xor(ti, o);
      bool take = (ov > tv) || (ov == tv && oi < ti);
      tv = take ? ov : tv;
      ti = take ? oi : ti;
    }
    if (lane == 0) { sv[wave] = tv; si[wave] = ti; }
    __syncthreads();

    if (wave == 0) {
      // ---- cross-wave reduction (16 entries, lanes 0..15) ----
      float v8 = (lane < 16) ? sv[lane] : -FLT_MAX;
      int   i8 = (lane < 16) ? si[lane] : 0x7FFFFFFF;
      #pragma unroll
      for (int o = 8; o > 0; o >>= 1) {
        float ov = __shfl_xor(v8, o);
        int   oi = __shfl_xor(i8, o);
        bool take = (ov > v8) || (ov == v8 && oi < i8);
        v8 = take ? ov : v8;
        i8 = take ? oi : i8;
      }

      if (lane == 0) {
        // fetch block-winner coords (L3-warm) BEFORE publish: overlaps skew
        const float* pw = P + (size_t)i8 * 3;
        float fx = pw[0], fy = pw[1], fz = pw[2];
        Slot* s = &slots[(b * 2 + (it & 1)) * BPB + c];
        unsigned long long xy =
            (unsigned long long)__float_as_uint(fx) |
            ((unsigned long long)__float_as_uint(fy) << 32);
        __hip_atomic_store(&s->xy, xy, __ATOMIC_RELAXED, __HIP_MEMORY_SCOPE_AGENT);
        __hip_atomic_store(&s->z, __float_as_uint(fz), __ATOMIC_RELAXED, __HIP_MEMORY_SCOPE_AGENT);
        unsigned long long tg =
            ((unsigned long long)__float_as_uint(v8) << 32) |
            ((unsigned long long)(unsigned)i8 << 7) | (unsigned)it;
        __hip_atomic_store(&s->tag, tg, __ATOMIC_RELEASE, __HIP_MEMORY_SCOPE_AGENT);
      }

      // ---- poll the 8 block candidates (lanes 0..7, parallel) ----
      float cv = -FLT_MAX, fx = 0.f, fy = 0.f, fz = 0.f;
      int   ci = 0x7FFFFFFF;
      if (lane < BPB) {
        Slot* r = &slots[(b * 2 + (it & 1)) * BPB + lane];
        unsigned long long t = 0; int sp = 0;
        for (;;) {
          t = __hip_atomic_load(&r->tag, __ATOMIC_ACQUIRE, __HIP_MEMORY_SCOPE_AGENT);
          if ((t & 127ull) == (unsigned long long)(unsigned)it) break;
          if (++sp > SPIN_CAP) break;       // wrong answer >> dead container
          __builtin_amdgcn_s_sleep(1);
        }
        cv = __uint_as_float((unsigned)(t >> 32));
        ci = (int)((t >> 7) & 0x3FFFF);
        unsigned long long xy =
            __hip_atomic_load(&r->xy, __ATOMIC_RELAXED, __HIP_MEMORY_SCOPE_AGENT);
        fx = __uint_as_float((unsigned)xy);
        fy = __uint_as_float((unsigned)(xy >> 32));
        fz = __uint_as_float(
            __hip_atomic_load(&r->z, __ATOMIC_RELAXED, __HIP_MEMORY_SCOPE_AGENT));
      }
      #pragma unroll
      for (int o = 4; o > 0; o >>= 1) {
        float ov = __shfl_xor(cv, o);
        int   oi = __shfl_xor(ci, o);
        float ox = __shfl_xor(fx, o);
        float oy = __shfl_xor(fy, o);
        float oz = __shfl_xor(fz, o);
        bool take = (ov > cv) || (ov == cv && oi < ci);
        cv = take ? ov : cv;
        ci = take ? oi : ci;
        fx = take ? ox : fx;
        fy = take ? oy : fy;
        fz = take ? oz : fz;
      }
      if (lane == 0) {
        wfar = ci; wx = fx; wy = fy; wz = fz;
        if (c == 0) out[b * M_ + it] = ci;
      }
    }
    __syncthreads();
    far = wfar; cx = wx; cy = wy; cz = wz;
  }
}

extern "C" void kernel_launch(void* const* d_in, const int* in_sizes, int n_in,
                              void* d_out, int out_size, void* d_ws, size_t ws_size,
                              hipStream_t stream) {
  const float* pts   = (const float*)d_in[0];
  int*         out   = (int*)d_out;
  Slot*        slots = (Slot*)d_ws;

  // zero slot tags every launch (tag 0 never matches it>=1); capture-safe
  hipMemsetAsync(d_ws, 0, (size_t)B_ * 2 * BPB * sizeof(Slot), stream);

  // 144 KiB LDS/block -> 1 block/CU; grid == 256 == CU count -> co-resident.
  fps_kernel<<<dim3(B_ * BPB), dim3(T_), 0, stream>>>(pts, out, slots);
}